// Round 9
// baseline (195.616 us; speedup 1.0000x reference)
//
#include <hip/hip_runtime.h>
#include <math.h>

// ---------------------------------------------------------------------------
// SocialLstm: T=24, N=2048, INPUT_DIM=2, HIDDEN=64, MEDIATE=128, SOCIAL=64,
// OUT_DIM=2, N_SIZE=2, CELL=0.3, T_obs=9, T_pred=19, WIN=9.
//
// R9 (on R8's 101us k_persist / 195 total): per-step critical-path surgery.
//  * 2 barriers/step (was 4): frag-building fused into the post-LSTM phase;
//    hs/cvs strictly wave-local (wave w owns agents w, w+8) -> in-wave LDS
//    ordering replaces barriers.
//  * full-wave poll: 64 lanes x 1 tagged word/partner (1 round trip).
//  * e-dot: 1 col/lane (64 lanes), stride-65 conflict-free, unroll 8.
//  * out[t-2] r-feedback in wave-uniform regs (oprev) -- olocal LDS gone.
// MFMA hi/lo bf16 split (ZhWh+ZlWh+ZhWl) verified R3-R8, absmax ~2e-3.
// ---------------------------------------------------------------------------

#define N_AG   2048
#define STEPS  20
#define CAP    12

typedef short short8 __attribute__((ext_vector_type(8)));
typedef float f32x4  __attribute__((ext_vector_type(4)));
union FU { uint4 q; short8 v; };

__device__ __forceinline__ unsigned short bf16rne(float x) {
    unsigned u = __float_as_uint(x);
    unsigned r = (u + 0x7fff + ((u >> 16) & 1)) >> 16;
    return (unsigned short)r;
}

__device__ __forceinline__ void pack8(const float* v, uint4& hq, uint4& lq) {
    unsigned uh[4], ul[4];
    #pragma unroll
    for (int w = 0; w < 4; w++) {
        float v0 = v[2 * w], v1 = v[2 * w + 1];
        unsigned short h0 = bf16rne(v0), h1 = bf16rne(v1);
        float f0 = __uint_as_float(((unsigned)h0) << 16);
        float f1 = __uint_as_float(((unsigned)h1) << 16);
        unsigned short l0 = bf16rne(v0 - f0), l1 = bf16rne(v1 - f1);
        uh[w] = (unsigned)h0 | ((unsigned)h1 << 16);
        ul[w] = (unsigned)l0 | ((unsigned)l1 << 16);
    }
    hq = make_uint4(uh[0], uh[1], uh[2], uh[3]);
    lq = make_uint4(ul[0], ul[1], ul[2], ul[3]);
}

__device__ __forceinline__ int khash(int k) {
    return (int)(((unsigned)k * 2654435761u) >> 21);   // 11-bit bucket
}

__device__ __forceinline__ float fsigm(float x) {
    return __builtin_amdgcn_rcpf(1.f + __expf(-x));
}
__device__ __forceinline__ float ftanh(float x) {
    float e = __expf(2.f * x);
    return 1.f - 2.f * __builtin_amdgcn_rcpf(e + 1.f);
}

// ---------------------------------------------------------------------------
// k_pre: blocks 0..19 = per-step hash match (+ need flags); block 20 = We
// fold; blocks 21..52 = zero out tail frames. (unchanged, verified R6-R8)
// ---------------------------------------------------------------------------
__global__ __launch_bounds__(512) void k_pre(
    const float* __restrict__ X, const float* __restrict__ masks,
    const float* __restrict__ Wsoc,
    float* __restrict__ Wef, int* __restrict__ mcnt, int* __restrict__ midx,
    int* __restrict__ need, float* __restrict__ otail)
{
    const int bx = blockIdx.x, tid = threadIdx.x;

    if (bx >= 21) {
        otail[(bx - 21) * 512 + tid] = 0.f;
        return;
    }
    if (bx == 20) {
        for (int i = tid; i < 4096; i += 512) {
            int s = i >> 6, k = i & 63;
            float a = 0.f;
            #pragma unroll
            for (int w = 0; w < 9; w++) a += Wsoc[s * 576 + w * 64 + k];
            Wef[i] = a;
        }
        return;
    }

    __shared__ int kk[N_AG];
    __shared__ int head[N_AG];
    __shared__ int nxt[N_AG];
    __shared__ float red[512];
    const int t = bx;
    const float* Xt = X + t * N_AG * 2;

    float mnx = 1e30f, mny = 1e30f;
    for (int i = tid; i < N_AG; i += 512) {
        mnx = fminf(mnx, Xt[2 * i]);
        mny = fminf(mny, Xt[2 * i + 1]);
    }
    red[tid] = mnx; __syncthreads();
    for (int s = 256; s > 0; s >>= 1) { if (tid < s) red[tid] = fminf(red[tid], red[tid + s]); __syncthreads(); }
    float ltx = red[0]; __syncthreads();
    red[tid] = mny; __syncthreads();
    for (int s = 256; s > 0; s >>= 1) { if (tid < s) red[tid] = fminf(red[tid], red[tid + s]); __syncthreads(); }
    float lty = red[0]; __syncthreads();
    ltx -= 1.2f;   // margin = 2*N_SIZE*CELL
    lty -= 1.2f;

    for (int i = tid; i < N_AG; i += 512) {
        float m = masks[t * N_AG + i];
        int px = (int)floorf((Xt[2 * i]     - ltx) / 0.3f);
        int py = (int)floorf((Xt[2 * i + 1] - lty) / 0.3f);
        int im = (int)m;
        px *= im; py *= im;
        kk[i] = px * 65536 + py;    // masked -> 0; real agents have px,py >= 4
        head[i] = -1;
        if (t >= 1) need[(t - 1) * N_AG + i] = 0;
    }
    __syncthreads();
    for (int j = tid; j < N_AG; j += 512) {
        int kj = kk[j];
        if (kj != 0) nxt[j] = atomicExch(&head[khash(kj)], j);
    }
    __syncthreads();
    for (int i = tid; i < N_AG; i += 512) {
        int ki = kk[i];
        int cnt = 0;
        int base = (t * N_AG + i) * CAP;
        if (ki != 0) {
            int tkey = ki - 65537;
            int lst[CAP];
            for (int j = head[khash(tkey)]; j >= 0; j = nxt[j]) {
                if (kk[j] == tkey) { if (cnt < CAP) lst[cnt] = j; cnt++; }
            }
            if (cnt > CAP) cnt = CAP;
            for (int a = 1; a < cnt; a++) {           // ascending j = ref sum order
                int v = lst[a]; int b = a - 1;
                while (b >= 0 && lst[b] > v) { lst[b + 1] = lst[b]; b--; }
                lst[b + 1] = v;
            }
            for (int a = 0; a < cnt; a++) {
                midx[base + a] = lst[a];
                if (t >= 1) need[(t - 1) * N_AG + lst[a]] = 1;
            }
        }
        mcnt[t * N_AG + i] = cnt;
    }
}

// ---------------------------------------------------------------------------
struct KP {
    const float *X, *masks, *h_in, *c_in;
    const float *Win, *bin, *bsoc, *Wih, *Whh, *bih, *bhh, *Wout, *bout;
    const float *Wef;
    const int *mcnt, *midx, *need;
    float *out;
    unsigned long long *hist;    // 19 slices x [2048][64] of (tag<<32|f32bits)
};

__global__ __launch_bounds__(512, 2) void k_persist(KP p)
{
    __shared__ __align__(16) uint4 zshq[544];     // frag slot s5*17 + m
    __shared__ __align__(16) uint4 zslq[544];
    __shared__ float gbuf[16][258];
    __shared__ float cvs[16][64];                 // wave-local rows
    __shared__ float hs[16][68];                  // wave-local rows
    __shared__ float sWefP[64 * 65];
    __shared__ float2 sWinP[16 * 17];
    __shared__ float sBinP[16 * 9];
    __shared__ float sX[11][16][2];
    __shared__ float sMask[STEPS][16];
    __shared__ int   sCnt[STEPS][16];
    __shared__ int   sNeed[19][16];
    __shared__ int   sMidx[STEPS][16][CAP];
    __shared__ float sBsoc[64], sBc[256], sWout[128], sBout[2];
    __shared__ uint4 sE0h[8], sE0l[8];

    const int tid   = threadIdx.x;
    const int bx    = blockIdx.x;
    const int wbase = bx * 16;
    const int wv    = tid >> 6, lane = tid & 63;
    const int mA    = lane & 15, quad = lane >> 4;
    const int nt0   = 2 * wv;
    const int m0    = wv, m1 = wv + 8;            // agents owned by this wave

    // =================== prologue: stashes ===================
    if (tid < 256) sBc[tid] = p.bih[tid] + p.bhh[tid];
    if (tid < 128) {
        sWout[tid] = p.Wout[tid];
        int c = tid;
        sWinP[(c >> 3) * 17 + (c & 7)] = make_float2(p.Win[2 * c], p.Win[2 * c + 1]);
        sBinP[(c >> 3) * 9 + (c & 7)] = p.bin[c];
    }
    if (tid < 64) sBsoc[tid] = p.bsoc[tid];
    if (tid < 2)  sBout[tid] = p.bout[tid];
    if (tid < 8) {
        float v[8];
        #pragma unroll
        for (int j = 0; j < 8; j++) v[j] = fmaxf(p.bsoc[tid * 8 + j], 0.f);
        pack8(v, sE0h[tid], sE0l[tid]);
    }
    if (tid < 352) { int tt = tid / 32, r = tid % 32;
                     sX[tt][r >> 1][r & 1] = p.X[tt * (N_AG * 2) + (wbase + (r >> 1)) * 2 + (r & 1)]; }
    if (tid < 320) { int tt = tid / 16, m2 = tid % 16;
                     sMask[tt][m2] = p.masks[tt * N_AG + wbase + m2];
                     sCnt[tt][m2]  = p.mcnt[tt * N_AG + wbase + m2]; }
    if (tid < 304) { int s = tid / 16, m2 = tid % 16;
                     sNeed[s][m2] = p.need[s * N_AG + wbase + m2]; }
    for (int i = tid; i < 4096; i += 512) sWefP[(i >> 6) * 65 + (i & 63)] = p.Wef[i];
    for (int i = tid; i < STEPS * 16 * CAP; i += 512) {
        int tt = i / (16 * CAP), r = i % (16 * CAP), m2 = r / CAP, n = r % CAP;
        sMidx[tt][m2][n] = p.midx[(tt * N_AG + wbase + m2) * CAP + n];
    }

    // own h (wave-local LDS rows) + c (registers)
    float c0, c1;
    hs[m0][lane] = p.h_in[(wbase + m0) * 64 + lane];
    hs[m1][lane] = p.h_in[(wbase + m1) * 64 + lane];
    c0 = p.c_in[(wbase + m0) * 64 + lane];
    c1 = p.c_in[(wbase + m1) * 64 + lane];

    // register-resident W fragments (hi/lo split), loaded once
    FU wh[2][8], wl[2][8];
    #pragma unroll
    for (int e = 0; e < 2; e++) {
        int g = (nt0 + e) * 16 + mA;
        #pragma unroll
        for (int kt = 0; kt < 8; kt++) {
            int k0 = kt * 32 + quad * 8;        // 8-run never crosses the 192 boundary
            const float* src = (k0 < 192) ? (p.Wih + g * 192 + k0)
                                          : (p.Whh + g * 64 + (k0 - 192));
            float v[8];
            #pragma unroll
            for (int j = 0; j < 8; j++) v[j] = src[j];
            pack8(v, wh[e][kt].q, wl[e][kt].q);
        }
    }

    float oprev0x = 0.f, oprev0y = 0.f, oprev1x = 0.f, oprev1y = 0.f;

    __syncthreads();   // stashes visible

    // =================== prologue: build frags for t=0 ===================
    {
        // lanes 0..31: r-frags; 32..47: h-frags; 48..63: e-const frags
        if (lane < 32) {
            int a = lane & 1, s5r = lane >> 1;
            int m = a ? m1 : m0;
            float px = sX[0][m][0], py = sX[0][m][1];
            float v[8];
            #pragma unroll
            for (int j = 0; j < 8; j++) {
                float2 w2 = sWinP[s5r * 17 + j];
                v[j] = fmaxf(w2.x * px + w2.y * py + sBinP[s5r * 9 + j], 0.f);
            }
            pack8(v, zshq[s5r * 17 + m], zslq[s5r * 17 + m]);
        } else if (lane < 48) {
            int idx = lane - 32, a = idx & 1, s58 = idx >> 1;
            int m = a ? m1 : m0;
            float v[8];
            #pragma unroll
            for (int j = 0; j < 8; j++) v[j] = hs[m][s58 * 8 + j];
            pack8(v, zshq[(24 + s58) * 17 + m], zslq[(24 + s58) * 17 + m]);
        } else {
            int idx = lane - 48, a = idx & 1, s58 = idx >> 1;
            int m = a ? m1 : m0;
            if (sCnt[0][m] == 0) {
                zshq[(16 + s58) * 17 + m] = sE0h[s58];
                zslq[(16 + s58) * 17 + m] = sE0l[s58];
            }
        }
        // matched agents at t=0: gather from h_in (coherent, plain loads)
        #pragma unroll
        for (int a = 0; a < 2; a++) {
            int m = a ? m1 : m0;
            int cnt = sCnt[0][m];
            if (cnt > 0) {
                float cv = 0.f;
                for (int n = 0; n < cnt; n++)
                    cv += p.h_in[sMidx[0][m][n] * 64 + lane];
                cvs[m][lane] = cv;
                float acc = sBsoc[lane];
                const float* wp = &sWefP[lane * 65];
                #pragma unroll 8
                for (int k = 0; k < 64; k++) acc += cvs[m][k] * wp[k];
                acc = fmaxf(acc, 0.f);
                float v[8];
                #pragma unroll
                for (int jj = 0; jj < 8; jj++)
                    v[jj] = __shfl(acc, (lane & 7) * 8 + jj, 64);
                if (lane < 8)
                    pack8(v, zshq[(16 + lane) * 17 + m], zslq[(16 + lane) * 17 + m]);
            }
        }
    }
    __syncthreads();   // t=0 frags visible

    // =================== recurrence: 2 barriers/step ===================
    #pragma unroll 1
    for (int t = 0; t < STEPS; t++) {
        // ---- C: GEMM, all 8 k-tiles, register-resident W ----
        {
            f32x4 a0v = {0.f, 0.f, 0.f, 0.f};
            f32x4 a1v = {0.f, 0.f, 0.f, 0.f};
            #pragma unroll
            for (int kt = 0; kt < 8; kt++) {
                int fi = (kt * 4 + quad) * 17 + mA;
                FU az, bz;
                az.q = zshq[fi];
                bz.q = zslq[fi];
                a0v = __builtin_amdgcn_mfma_f32_16x16x32_bf16(az.v, wh[0][kt].v, a0v, 0, 0, 0);
                a1v = __builtin_amdgcn_mfma_f32_16x16x32_bf16(az.v, wh[1][kt].v, a1v, 0, 0, 0);
                a0v = __builtin_amdgcn_mfma_f32_16x16x32_bf16(bz.v, wh[0][kt].v, a0v, 0, 0, 0);
                a1v = __builtin_amdgcn_mfma_f32_16x16x32_bf16(bz.v, wh[1][kt].v, a1v, 0, 0, 0);
                a0v = __builtin_amdgcn_mfma_f32_16x16x32_bf16(az.v, wl[0][kt].v, a0v, 0, 0, 0);
                a1v = __builtin_amdgcn_mfma_f32_16x16x32_bf16(az.v, wl[1][kt].v, a1v, 0, 0, 0);
            }
            #pragma unroll
            for (int r = 0; r < 4; r++) {
                int row = quad * 4 + r;
                gbuf[row][nt0 * 16 + mA]       = a0v[r];
                gbuf[row][(nt0 + 1) * 16 + mA] = a1v[r];
            }
        }
        __syncthreads();   // bar1: gbuf visible

        // ---- fused: LSTM + publish + out + next-frags + next-poll ----
        {
            const int hid = lane;
            float hn0, hn1;
            {
                float gi = gbuf[m0][hid]       + sBc[hid];
                float gf = gbuf[m0][64 + hid]  + sBc[64 + hid];
                float gR = gbuf[m0][128 + hid] + sBc[128 + hid];
                float go = gbuf[m0][192 + hid] + sBc[192 + hid];
                float cn = fsigm(gf) * c0 + fsigm(gi) * ftanh(gR);
                hn0 = fsigm(go) * ftanh(cn);
                c0 = cn;
            }
            {
                float gi = gbuf[m1][hid]       + sBc[hid];
                float gf = gbuf[m1][64 + hid]  + sBc[64 + hid];
                float gR = gbuf[m1][128 + hid] + sBc[128 + hid];
                float go = gbuf[m1][192 + hid] + sBc[192 + hid];
                float cn = fsigm(gf) * c1 + fsigm(gi) * ftanh(gR);
                hn1 = fsigm(go) * ftanh(cn);
                c1 = cn;
            }
            // publish needed h early (consumers poll from other blocks)
            if (t <= 18) {
                unsigned long long* hp = p.hist + (size_t)t * (N_AG * 64);
                unsigned long long tg = ((unsigned long long)(t + 1)) << 32;
                if (sNeed[t][m0])
                    __hip_atomic_store(&hp[(wbase + m0) * 64 + hid],
                                       tg | (unsigned long long)__float_as_uint(hn0),
                                       __ATOMIC_RELAXED, __HIP_MEMORY_SCOPE_AGENT);
                if (sNeed[t][m1])
                    __hip_atomic_store(&hp[(wbase + m1) * 64 + hid],
                                       tg | (unsigned long long)__float_as_uint(hn1),
                                       __ATOMIC_RELAXED, __HIP_MEMORY_SCOPE_AGENT);
            }
            hs[m0][hid] = hn0;           // wave-local
            hs[m1][hid] = hn1;

            // out: butterfly (all lanes end with all 4 sums)
            float w0 = sWout[hid], w1 = sWout[64 + hid];
            float p00 = hn0 * w0, p01 = hn0 * w1;
            float p10 = hn1 * w0, p11 = hn1 * w1;
            #pragma unroll
            for (int off = 32; off >= 1; off >>= 1) {
                p00 += __shfl_xor(p00, off);
                p01 += __shfl_xor(p01, off);
                p10 += __shfl_xor(p10, off);
                p11 += __shfl_xor(p11, off);
            }
            float mk0 = sMask[t][m0], mk1 = sMask[t][m1];
            float o00 = (p00 + sBout[0]) * mk0, o01 = (p01 + sBout[1]) * mk0;
            float o10 = (p10 + sBout[0]) * mk1, o11 = (p11 + sBout[1]) * mk1;
            if (lane == 0)
                *(float2*)&p.out[(t * N_AG + wbase + m0) * 2] = make_float2(o00, o01);
            if (lane == 1)
                *(float2*)&p.out[(t * N_AG + wbase + m1) * 2] = make_float2(o10, o11);

            if (t < STEPS - 1) {
                const int tn = t + 1;
                // frag duties (uses oprev = out[t-1] for tn>=11)
                if (lane < 32) {
                    int a = lane & 1, s5r = lane >> 1;
                    int m = a ? m1 : m0;
                    float px, py;
                    if (tn <= 10) { px = sX[tn][m][0]; py = sX[tn][m][1]; }
                    else          { px = a ? oprev1x : oprev0x;
                                    py = a ? oprev1y : oprev0y; }
                    float v[8];
                    #pragma unroll
                    for (int j = 0; j < 8; j++) {
                        float2 w2 = sWinP[s5r * 17 + j];
                        v[j] = fmaxf(w2.x * px + w2.y * py + sBinP[s5r * 9 + j], 0.f);
                    }
                    pack8(v, zshq[s5r * 17 + m], zslq[s5r * 17 + m]);
                } else if (lane < 48) {
                    int idx = lane - 32, a = idx & 1, s58 = idx >> 1;
                    int m = a ? m1 : m0;
                    float v[8];
                    #pragma unroll
                    for (int j = 0; j < 8; j++) v[j] = hs[m][s58 * 8 + j];
                    pack8(v, zshq[(24 + s58) * 17 + m], zslq[(24 + s58) * 17 + m]);
                } else {
                    int idx = lane - 48, a = idx & 1, s58 = idx >> 1;
                    int m = a ? m1 : m0;
                    if (sCnt[tn][m] == 0) {
                        zshq[(16 + s58) * 17 + m] = sE0h[s58];
                        zslq[(16 + s58) * 17 + m] = sE0l[s58];
                    }
                }
                // poll for tn's matched owned agents (full wave per agent)
                #pragma unroll
                for (int a = 0; a < 2; a++) {
                    int m = a ? m1 : m0;
                    int cnt = sCnt[tn][m];
                    if (cnt > 0) {
                        const unsigned long long* hb =
                            p.hist + (size_t)t * (N_AG * 64);
                        const unsigned tagw = (unsigned)tn;
                        float cv = 0.f;
                        for (int n = 0; n < cnt; n++) {
                            int r = sMidx[tn][m][n];
                            unsigned long long wd;
                            do { wd = __hip_atomic_load(&hb[r * 64 + lane],
                                     __ATOMIC_RELAXED, __HIP_MEMORY_SCOPE_AGENT);
                            } while ((unsigned)(wd >> 32) != tagw);
                            cv += __uint_as_float((unsigned)wd);
                        }
                        cvs[m][lane] = cv;           // wave-local
                        float acc = sBsoc[lane];
                        const float* wp = &sWefP[lane * 65];
                        #pragma unroll 8
                        for (int k = 0; k < 64; k++) acc += cvs[m][k] * wp[k];
                        acc = fmaxf(acc, 0.f);
                        float v[8];
                        #pragma unroll
                        for (int jj = 0; jj < 8; jj++)
                            v[jj] = __shfl(acc, (lane & 7) * 8 + jj, 64);
                        if (lane < 8)
                            pack8(v, zshq[(16 + lane) * 17 + m],
                                     zslq[(16 + lane) * 17 + m]);
                    }
                }
            }
            oprev0x = o00; oprev0y = o01;
            oprev1x = o10; oprev1y = o11;
        }
        __syncthreads();   // bar2: t+1 frags visible
    }
}

// ---------------------------------------------------------------------------
extern "C" void kernel_launch(void* const* d_in, const int* in_sizes, int n_in,
                              void* d_out, int out_size, void* d_ws, size_t ws_size,
                              hipStream_t stream)
{
    KP kp;
    kp.X     = (const float*)d_in[0];
    kp.masks = (const float*)d_in[1];
    kp.h_in  = (const float*)d_in[2];
    kp.c_in  = (const float*)d_in[3];
    // d_in[4] = Y (unused), d_in[5] = T_obs (=9), d_in[6] = T_pred (=19)
    kp.Win   = (const float*)d_in[7];
    kp.bin   = (const float*)d_in[8];
    const float* Wsoc = (const float*)d_in[9];
    kp.bsoc  = (const float*)d_in[10];
    kp.Wih   = (const float*)d_in[11];
    kp.Whh   = (const float*)d_in[12];
    kp.bih   = (const float*)d_in[13];
    kp.bhh   = (const float*)d_in[14];
    kp.Wout  = (const float*)d_in[15];
    kp.bout  = (const float*)d_in[16];
    kp.out   = (float*)d_out;

    unsigned long long* hist = (unsigned long long*)d_ws;   // 19*2048*64 (8B each)
    float* Wef = (float*)(hist + 19 * N_AG * 64);           // 4096
    int*   need = (int*)(Wef + 4096);                       // 19*2048
    int*   mcnt = need + 19 * N_AG;                         // 20*2048
    int*   midx = mcnt + STEPS * N_AG;                      // 20*2048*CAP

    kp.hist = hist; kp.Wef = Wef; kp.need = need; kp.mcnt = mcnt; kp.midx = midx;

    k_pre<<<53, 512, 0, stream>>>(kp.X, kp.masks, Wsoc, Wef, mcnt, midx, need,
                                  kp.out + 20 * N_AG * 2);

    k_persist<<<128, 512, 0, stream>>>(kp);
}